// Round 1
// baseline (979.226 us; speedup 1.0000x reference)
//
#include <hip/hip_runtime.h>
#include <math.h>

// ---------------------------------------------------------------------------
// GCN: h1 = relu(Agg(x@W1)+b1); h2 = relu(Agg(h1@W2)+b2); out = sigmoid(h2@Wfc+bfc)
// Agg(xl)[dst] = sum_{src->dst} xl[src]*dinv[src]*dinv[dst] + xl[dst]*dinv[dst]^2
// deg includes the self-loop (deg = in_count + 1), dinv = rsqrt(deg).
// Strategy: build CSR (by dst) once, pull-based gather for both layers.
// ---------------------------------------------------------------------------

__global__ void k_zero_int(int* __restrict__ p, int n) {
    int i = blockIdx.x * blockDim.x + threadIdx.x;
    if (i < n) p[i] = 0;
}

__global__ void k_count(const int* __restrict__ col, int E, int* __restrict__ counts) {
    int e = blockIdx.x * blockDim.x + threadIdx.x;
    if (e < E) atomicAdd(&counts[col[e]], 1);
}

__global__ void k_dinv(const int* __restrict__ counts, float* __restrict__ dinv, int N) {
    int i = blockIdx.x * blockDim.x + threadIdx.x;
    if (i < N) dinv[i] = rsqrtf((float)(counts[i] + 1));  // +1 self loop
}

// Single-block exclusive scan: 1024 threads, chunk-per-thread.
__global__ __launch_bounds__(1024) void k_scan(const int* __restrict__ counts,
                                               int* __restrict__ row_off,
                                               int* __restrict__ cursor, int N) {
    __shared__ int sums[1024];
    int tid = threadIdx.x;
    int chunk = (N + 1023) / 1024;
    int start = tid * chunk;
    int end   = min(start + chunk, N);
    int s = 0;
    for (int i = start; i < end; ++i) s += counts[i];
    sums[tid] = s;
    __syncthreads();
    // Hillis-Steele inclusive scan over the 1024 chunk sums
    for (int off = 1; off < 1024; off <<= 1) {
        int v = (tid >= off) ? sums[tid - off] : 0;
        __syncthreads();
        sums[tid] += v;
        __syncthreads();
    }
    int carry = (tid > 0) ? sums[tid - 1] : 0;  // exclusive prefix of this chunk
    for (int i = start; i < end; ++i) {
        row_off[i] = carry;
        cursor[i]  = carry;
        carry += counts[i];
    }
    if (tid == 1023) row_off[N] = carry;  // == E
}

__global__ void k_fill(const int* __restrict__ row, const int* __restrict__ col, int E,
                       int* __restrict__ cursor, int* __restrict__ csr_src) {
    int e = blockIdx.x * blockDim.x + threadIdx.x;
    if (e < E) {
        int pos = atomicAdd(&cursor[col[e]], 1);
        csr_src[pos] = row[e];
    }
}

// out[node][lane] = sum_k x[node][k] * W[k][lane];  lane = output feature (H=64).
// W staged in LDS once per block; grid-stride over nodes.
template <int D>
__global__ __launch_bounds__(256) void k_gemm(const float* __restrict__ x,
                                              const float* __restrict__ W,
                                              float* __restrict__ out, int N) {
    __shared__ float sW[D * 64];
    for (int i = threadIdx.x; i < D * 64; i += 256) sW[i] = W[i];
    __syncthreads();
    int wave = threadIdx.x >> 6, lane = threadIdx.x & 63;
    for (int node = blockIdx.x * 4 + wave; node < N; node += gridDim.x * 4) {
        const float* xr = x + (size_t)node * D;
        float acc = 0.f;
#pragma unroll 8
        for (int k = 0; k < D; k += 4) {
            float4 xv = *(const float4*)(xr + k);  // wave-uniform broadcast load
            acc = fmaf(xv.x, sW[(k + 0) * 64 + lane], acc);
            acc = fmaf(xv.y, sW[(k + 1) * 64 + lane], acc);
            acc = fmaf(xv.z, sW[(k + 2) * 64 + lane], acc);
            acc = fmaf(xv.w, sW[(k + 3) * 64 + lane], acc);
        }
        out[(size_t)node * 64 + lane] = acc;
    }
}

// One wave per dst node; lane = feature. Pull-gather over CSR, fused bias+ReLU.
__global__ __launch_bounds__(256) void k_agg(const float* __restrict__ xl,
                                             const int* __restrict__ row_off,
                                             const int* __restrict__ csr_src,
                                             const float* __restrict__ dinv,
                                             const float* __restrict__ bias,
                                             float* __restrict__ out, int N) {
    int wave = threadIdx.x >> 6, lane = threadIdx.x & 63;
    int node = blockIdx.x * 4 + wave;
    if (node >= N) return;
    int beg = row_off[node], end = row_off[node + 1];
    float di = dinv[node];
    float acc = xl[(size_t)node * 64 + lane] * di * di;  // self loop
    for (int e = beg; e < end; ++e) {
        int src = csr_src[e];                       // wave-uniform broadcast
        float w = dinv[src] * di;
        acc = fmaf(xl[(size_t)src * 64 + lane], w, acc);
    }
    out[(size_t)node * 64 + lane] = fmaxf(acc + bias[lane], 0.f);
}

// Layer-2 aggregation with the final FC + sigmoid fused (64-lane reduction).
__global__ __launch_bounds__(256) void k_agg_fc(const float* __restrict__ xl,
                                                const int* __restrict__ row_off,
                                                const int* __restrict__ csr_src,
                                                const float* __restrict__ dinv,
                                                const float* __restrict__ bias,
                                                const float* __restrict__ Wfc,
                                                const float* __restrict__ bfc,
                                                float* __restrict__ out, int N) {
    int wave = threadIdx.x >> 6, lane = threadIdx.x & 63;
    int node = blockIdx.x * 4 + wave;
    if (node >= N) return;
    int beg = row_off[node], end = row_off[node + 1];
    float di = dinv[node];
    float acc = xl[(size_t)node * 64 + lane] * di * di;
    for (int e = beg; e < end; ++e) {
        int src = csr_src[e];
        float w = dinv[src] * di;
        acc = fmaf(xl[(size_t)src * 64 + lane], w, acc);
    }
    float h = fmaxf(acc + bias[lane], 0.f);
    float v = h * Wfc[lane];
#pragma unroll
    for (int m = 32; m >= 1; m >>= 1) v += __shfl_xor(v, m, 64);
    if (lane == 0) out[node] = 1.f / (1.f + expf(-(v + bfc[0])));
}

extern "C" void kernel_launch(void* const* d_in, const int* in_sizes, int n_in,
                              void* d_out, int out_size, void* d_ws, size_t ws_size,
                              hipStream_t stream) {
    const float* x   = (const float*)d_in[0];
    const int*   ei  = (const int*)d_in[1];   // [2, E]: row then col
    const float* W1  = (const float*)d_in[2];
    const float* b1  = (const float*)d_in[3];
    const float* W2  = (const float*)d_in[4];
    const float* b2  = (const float*)d_in[5];
    const float* Wfc = (const float*)d_in[6];
    const float* bfc = (const float*)d_in[7];
    float* out = (float*)d_out;

    const int H = in_sizes[3];          // 64
    const int D = in_sizes[2] / H;      // 128
    const int N = in_sizes[0] / D;      // 100000
    const int E = in_sizes[1] / 2;      // 1600000
    const int* row = ei;
    const int* col = ei + E;

    // Workspace carve-up (256B aligned slices)
    char* p = (char*)d_ws;
    auto carve = [&](size_t bytes) {
        char* r = p;
        p += (bytes + 255) & ~(size_t)255;
        return (void*)r;
    };
    int*   counts  = (int*)carve((size_t)N * 4);
    int*   cursor  = (int*)carve((size_t)N * 4);
    int*   row_off = (int*)carve((size_t)(N + 1) * 4);
    float* dinv    = (float*)carve((size_t)N * 4);
    int*   csr_src = (int*)carve((size_t)E * 4);
    float* bufA    = (float*)carve((size_t)N * 64 * 4);
    float* bufB    = (float*)carve((size_t)N * 64 * 4);
    (void)ws_size;

    const int TB = 256;
    // 1. degree + normalization + CSR (shared by both layers)
    k_zero_int<<<(N + TB - 1) / TB, TB, 0, stream>>>(counts, N);
    k_count<<<(E + TB - 1) / TB, TB, 0, stream>>>(col, E, counts);
    k_dinv<<<(N + TB - 1) / TB, TB, 0, stream>>>(counts, dinv, N);
    k_scan<<<1, 1024, 0, stream>>>(counts, row_off, cursor, N);
    k_fill<<<(E + TB - 1) / TB, TB, 0, stream>>>(row, col, E, cursor, csr_src);

    int aggGrid = (N + 3) / 4;
    // 2. layer 1: xl = x@W1 ; h1 = relu(Agg(xl)+b1)
    k_gemm<128><<<1024, TB, 0, stream>>>(x, W1, bufA, N);
    k_agg<<<aggGrid, TB, 0, stream>>>(bufA, row_off, csr_src, dinv, b1, bufB, N);
    // 3. layer 2: xl2 = h1@W2 ; out = sigmoid(relu(Agg(xl2)+b2) @ Wfc + bfc)
    k_gemm<64><<<2048, TB, 0, stream>>>(bufB, W2, bufA, N);
    k_agg_fc<<<aggGrid, TB, 0, stream>>>(bufA, row_off, csr_src, dinv, b2, Wfc, bfc, out, N);
}

// Round 2
// 765.307 us; speedup vs baseline: 1.2795x; 1.2795x over previous
//
#include <hip/hip_runtime.h>
#include <math.h>

// ---------------------------------------------------------------------------
// GCN: h1 = relu(Agg(x@W1)+b1); h2 = relu(Agg(h1@W2)+b2); out = sigmoid(h2@Wfc+bfc)
// Agg(xl)[dst] = sum_{src->dst} xl[src]*dinv[src]*dinv[dst] + xl[dst]*dinv[dst]^2
// deg includes the self-loop (deg = in_count + 1), dinv = rsqrt(deg).
// Strategy: build CSR (by dst) once, pull-based gather for both layers.
// R2: replaced 232us single-block scan with 3-phase device-wide scan (<10us).
// ---------------------------------------------------------------------------

__global__ void k_zero_int(int* __restrict__ p, int n) {
    int i = blockIdx.x * blockDim.x + threadIdx.x;
    if (i < n) p[i] = 0;
}

__global__ void k_count(const int* __restrict__ col, int E, int* __restrict__ counts) {
    int e = blockIdx.x * blockDim.x + threadIdx.x;
    if (e < E) atomicAdd(&counts[col[e]], 1);
}

__global__ void k_dinv(const int* __restrict__ counts, float* __restrict__ dinv, int N) {
    int i = blockIdx.x * blockDim.x + threadIdx.x;
    if (i < N) dinv[i] = rsqrtf((float)(counts[i] + 1));  // +1 self loop
}

// --- three-phase exclusive scan of counts[N] -> row_off[N+1], cursor[N] ---
// Phase A: per-256-block sums (wave shuffle reduce + LDS).
__global__ __launch_bounds__(256) void k_blocksum(const int* __restrict__ counts, int N,
                                                  int* __restrict__ blockSums) {
    __shared__ int waveSum[4];
    int i = blockIdx.x * 256 + threadIdx.x;
    int v = (i < N) ? counts[i] : 0;
#pragma unroll
    for (int m = 32; m >= 1; m >>= 1) v += __shfl_xor(v, m, 64);
    int wave = threadIdx.x >> 6, lane = threadIdx.x & 63;
    if (lane == 0) waveSum[wave] = v;
    __syncthreads();
    if (threadIdx.x == 0)
        blockSums[blockIdx.x] = waveSum[0] + waveSum[1] + waveSum[2] + waveSum[3];
}

// Phase B: single-block exclusive scan of blockSums[NB] (NB <= 1024), in place.
__global__ __launch_bounds__(1024) void k_scan_blocks(int* __restrict__ blockSums, int NB) {
    __shared__ int s[1024];
    int tid = threadIdx.x;
    int v = (tid < NB) ? blockSums[tid] : 0;
    s[tid] = v;
    __syncthreads();
    for (int off = 1; off < 1024; off <<= 1) {
        int t = (tid >= off) ? s[tid - off] : 0;
        __syncthreads();
        s[tid] += t;
        __syncthreads();
    }
    if (tid < NB) blockSums[tid] = s[tid] - v;  // exclusive
}

// Phase C: intra-block exclusive scan + block offset -> row_off, cursor.
__global__ __launch_bounds__(256) void k_scan_write(const int* __restrict__ counts, int N, int E,
                                                    const int* __restrict__ blockOff,
                                                    int* __restrict__ row_off,
                                                    int* __restrict__ cursor) {
    __shared__ int s[256];
    int tid = threadIdx.x;
    int i = blockIdx.x * 256 + tid;
    int v = (i < N) ? counts[i] : 0;
    s[tid] = v;
    __syncthreads();
    for (int off = 1; off < 256; off <<= 1) {
        int t = (tid >= off) ? s[tid - off] : 0;
        __syncthreads();
        s[tid] += t;
        __syncthreads();
    }
    if (i < N) {
        int excl = blockOff[blockIdx.x] + s[tid] - v;
        row_off[i] = excl;
        cursor[i]  = excl;
        if (i == N - 1) row_off[N] = E;
    }
}

__global__ void k_fill(const int* __restrict__ row, const int* __restrict__ col, int E,
                       int* __restrict__ cursor, int* __restrict__ csr_src) {
    int e = blockIdx.x * blockDim.x + threadIdx.x;
    if (e < E) {
        int pos = atomicAdd(&cursor[col[e]], 1);
        csr_src[pos] = row[e];
    }
}

// out[node][lane] = sum_k x[node][k] * W[k][lane];  lane = output feature (H=64).
// W staged in LDS once per block; grid-stride over nodes.
template <int D>
__global__ __launch_bounds__(256) void k_gemm(const float* __restrict__ x,
                                              const float* __restrict__ W,
                                              float* __restrict__ out, int N) {
    __shared__ float sW[D * 64];
    for (int i = threadIdx.x; i < D * 64; i += 256) sW[i] = W[i];
    __syncthreads();
    int wave = threadIdx.x >> 6, lane = threadIdx.x & 63;
    for (int node = blockIdx.x * 4 + wave; node < N; node += gridDim.x * 4) {
        const float* xr = x + (size_t)node * D;
        float acc = 0.f;
#pragma unroll 8
        for (int k = 0; k < D; k += 4) {
            float4 xv = *(const float4*)(xr + k);  // wave-uniform broadcast load
            acc = fmaf(xv.x, sW[(k + 0) * 64 + lane], acc);
            acc = fmaf(xv.y, sW[(k + 1) * 64 + lane], acc);
            acc = fmaf(xv.z, sW[(k + 2) * 64 + lane], acc);
            acc = fmaf(xv.w, sW[(k + 3) * 64 + lane], acc);
        }
        out[(size_t)node * 64 + lane] = acc;
    }
}

// One wave per dst node; lane = feature. Pull-gather over CSR, fused bias+ReLU.
__global__ __launch_bounds__(256) void k_agg(const float* __restrict__ xl,
                                             const int* __restrict__ row_off,
                                             const int* __restrict__ csr_src,
                                             const float* __restrict__ dinv,
                                             const float* __restrict__ bias,
                                             float* __restrict__ out, int N) {
    int wave = threadIdx.x >> 6, lane = threadIdx.x & 63;
    int node = blockIdx.x * 4 + wave;
    if (node >= N) return;
    int beg = row_off[node], end = row_off[node + 1];
    float di = dinv[node];
    float acc = xl[(size_t)node * 64 + lane] * di * di;  // self loop
    for (int e = beg; e < end; ++e) {
        int src = csr_src[e];                       // wave-uniform broadcast
        float w = dinv[src] * di;
        acc = fmaf(xl[(size_t)src * 64 + lane], w, acc);
    }
    out[(size_t)node * 64 + lane] = fmaxf(acc + bias[lane], 0.f);
}

// Layer-2 aggregation with the final FC + sigmoid fused (64-lane reduction).
__global__ __launch_bounds__(256) void k_agg_fc(const float* __restrict__ xl,
                                                const int* __restrict__ row_off,
                                                const int* __restrict__ csr_src,
                                                const float* __restrict__ dinv,
                                                const float* __restrict__ bias,
                                                const float* __restrict__ Wfc,
                                                const float* __restrict__ bfc,
                                                float* __restrict__ out, int N) {
    int wave = threadIdx.x >> 6, lane = threadIdx.x & 63;
    int node = blockIdx.x * 4 + wave;
    if (node >= N) return;
    int beg = row_off[node], end = row_off[node + 1];
    float di = dinv[node];
    float acc = xl[(size_t)node * 64 + lane] * di * di;
    for (int e = beg; e < end; ++e) {
        int src = csr_src[e];
        float w = dinv[src] * di;
        acc = fmaf(xl[(size_t)src * 64 + lane], w, acc);
    }
    float h = fmaxf(acc + bias[lane], 0.f);
    float v = h * Wfc[lane];
#pragma unroll
    for (int m = 32; m >= 1; m >>= 1) v += __shfl_xor(v, m, 64);
    if (lane == 0) out[node] = 1.f / (1.f + expf(-(v + bfc[0])));
}

extern "C" void kernel_launch(void* const* d_in, const int* in_sizes, int n_in,
                              void* d_out, int out_size, void* d_ws, size_t ws_size,
                              hipStream_t stream) {
    const float* x   = (const float*)d_in[0];
    const int*   ei  = (const int*)d_in[1];   // [2, E]: row then col
    const float* W1  = (const float*)d_in[2];
    const float* b1  = (const float*)d_in[3];
    const float* W2  = (const float*)d_in[4];
    const float* b2  = (const float*)d_in[5];
    const float* Wfc = (const float*)d_in[6];
    const float* bfc = (const float*)d_in[7];
    float* out = (float*)d_out;

    const int H = in_sizes[3];          // 64
    const int D = in_sizes[2] / H;      // 128
    const int N = in_sizes[0] / D;      // 100000
    const int E = in_sizes[1] / 2;      // 1600000
    const int* row = ei;
    const int* col = ei + E;

    // Workspace carve-up (256B aligned slices)
    char* p = (char*)d_ws;
    auto carve = [&](size_t bytes) {
        char* r = p;
        p += (bytes + 255) & ~(size_t)255;
        return (void*)r;
    };
    int*   counts    = (int*)carve((size_t)N * 4);
    int*   cursor    = (int*)carve((size_t)N * 4);
    int*   row_off   = (int*)carve((size_t)(N + 1) * 4);
    float* dinv      = (float*)carve((size_t)N * 4);
    int*   csr_src   = (int*)carve((size_t)E * 4);
    int*   blockSums = (int*)carve((size_t)1024 * 4);
    float* bufA      = (float*)carve((size_t)N * 64 * 4);
    float* bufB      = (float*)carve((size_t)N * 64 * 4);
    (void)ws_size;

    const int TB = 256;
    const int NB = (N + TB - 1) / TB;   // 391 scan tiles (must be <= 1024)

    // 1. degree + normalization + CSR (shared by both layers)
    k_zero_int<<<(N + TB - 1) / TB, TB, 0, stream>>>(counts, N);
    k_count<<<(E + TB - 1) / TB, TB, 0, stream>>>(col, E, counts);
    k_dinv<<<(N + TB - 1) / TB, TB, 0, stream>>>(counts, dinv, N);
    k_blocksum<<<NB, TB, 0, stream>>>(counts, N, blockSums);
    k_scan_blocks<<<1, 1024, 0, stream>>>(blockSums, NB);
    k_scan_write<<<NB, TB, 0, stream>>>(counts, N, E, blockSums, row_off, cursor);
    k_fill<<<(E + TB - 1) / TB, TB, 0, stream>>>(row, col, E, cursor, csr_src);

    int aggGrid = (N + 3) / 4;
    // 2. layer 1: xl = x@W1 ; h1 = relu(Agg(xl)+b1)
    k_gemm<128><<<1024, TB, 0, stream>>>(x, W1, bufA, N);
    k_agg<<<aggGrid, TB, 0, stream>>>(bufA, row_off, csr_src, dinv, b1, bufB, N);
    // 3. layer 2: xl2 = h1@W2 ; out = sigmoid(relu(Agg(xl2)+b2) @ Wfc + bfc)
    k_gemm<64><<<2048, TB, 0, stream>>>(bufB, W2, bufA, N);
    k_agg_fc<<<aggGrid, TB, 0, stream>>>(bufA, row_off, csr_src, dinv, b2, Wfc, bfc, out, N);
}

// Round 3
// 594.809 us; speedup vs baseline: 1.6463x; 1.2866x over previous
//
#include <hip/hip_runtime.h>
#include <math.h>

// ---------------------------------------------------------------------------
// GCN: h1 = relu(Agg(x@W1)+b1); h2 = relu(Agg(h1@W2)+b2); out = sigmoid(h2@Wfc+bfc)
// Agg(xl)[dst] = dinv[dst] * ( sum_{src->dst} xl_s[src] + xl_s[dst] )
//   where xl_s[n] = (x@W)[n] * dinv[n]   (source-side norm folded into GEMM)
// deg includes the self-loop (deg = in_count + 1), dinv = rsqrt(deg).
// R2: 3-phase device-wide scan (was 232us single-block).
// R3: dinv folded into GEMM epilogue (kills per-edge random dinv[src] loads,
//     ~100MB HBM fetch/agg); edge loop unrolled x4 for MLP.
// ---------------------------------------------------------------------------

__global__ void k_zero_int(int* __restrict__ p, int n) {
    int i = blockIdx.x * blockDim.x + threadIdx.x;
    if (i < n) p[i] = 0;
}

__global__ void k_count(const int* __restrict__ col, int E, int* __restrict__ counts) {
    int e = blockIdx.x * blockDim.x + threadIdx.x;
    if (e < E) atomicAdd(&counts[col[e]], 1);
}

__global__ void k_dinv(const int* __restrict__ counts, float* __restrict__ dinv, int N) {
    int i = blockIdx.x * blockDim.x + threadIdx.x;
    if (i < N) dinv[i] = rsqrtf((float)(counts[i] + 1));  // +1 self loop
}

// --- three-phase exclusive scan of counts[N] -> row_off[N+1], cursor[N] ---
__global__ __launch_bounds__(256) void k_blocksum(const int* __restrict__ counts, int N,
                                                  int* __restrict__ blockSums) {
    __shared__ int waveSum[4];
    int i = blockIdx.x * 256 + threadIdx.x;
    int v = (i < N) ? counts[i] : 0;
#pragma unroll
    for (int m = 32; m >= 1; m >>= 1) v += __shfl_xor(v, m, 64);
    int wave = threadIdx.x >> 6, lane = threadIdx.x & 63;
    if (lane == 0) waveSum[wave] = v;
    __syncthreads();
    if (threadIdx.x == 0)
        blockSums[blockIdx.x] = waveSum[0] + waveSum[1] + waveSum[2] + waveSum[3];
}

__global__ __launch_bounds__(1024) void k_scan_blocks(int* __restrict__ blockSums, int NB) {
    __shared__ int s[1024];
    int tid = threadIdx.x;
    int v = (tid < NB) ? blockSums[tid] : 0;
    s[tid] = v;
    __syncthreads();
    for (int off = 1; off < 1024; off <<= 1) {
        int t = (tid >= off) ? s[tid - off] : 0;
        __syncthreads();
        s[tid] += t;
        __syncthreads();
    }
    if (tid < NB) blockSums[tid] = s[tid] - v;  // exclusive
}

__global__ __launch_bounds__(256) void k_scan_write(const int* __restrict__ counts, int N, int E,
                                                    const int* __restrict__ blockOff,
                                                    int* __restrict__ row_off,
                                                    int* __restrict__ cursor) {
    __shared__ int s[256];
    int tid = threadIdx.x;
    int i = blockIdx.x * 256 + tid;
    int v = (i < N) ? counts[i] : 0;
    s[tid] = v;
    __syncthreads();
    for (int off = 1; off < 256; off <<= 1) {
        int t = (tid >= off) ? s[tid - off] : 0;
        __syncthreads();
        s[tid] += t;
        __syncthreads();
    }
    if (i < N) {
        int excl = blockOff[blockIdx.x] + s[tid] - v;
        row_off[i] = excl;
        cursor[i]  = excl;
        if (i == N - 1) row_off[N] = E;
    }
}

__global__ void k_fill(const int* __restrict__ row, const int* __restrict__ col, int E,
                       int* __restrict__ cursor, int* __restrict__ csr_src) {
    int e = blockIdx.x * blockDim.x + threadIdx.x;
    if (e < E) {
        int pos = atomicAdd(&cursor[col[e]], 1);
        csr_src[pos] = row[e];
    }
}

// out[node][lane] = dinv[node] * sum_k x[node][k] * W[k][lane]; lane = feature.
// W staged in LDS once per block; grid-stride over nodes.
template <int D>
__global__ __launch_bounds__(256) void k_gemm(const float* __restrict__ x,
                                              const float* __restrict__ W,
                                              const float* __restrict__ dinv,
                                              float* __restrict__ out, int N) {
    __shared__ float sW[D * 64];
    for (int i = threadIdx.x; i < D * 64; i += 256) sW[i] = W[i];
    __syncthreads();
    int wave = threadIdx.x >> 6, lane = threadIdx.x & 63;
    for (int node = blockIdx.x * 4 + wave; node < N; node += gridDim.x * 4) {
        const float* xr = x + (size_t)node * D;
        float acc = 0.f;
#pragma unroll 8
        for (int k = 0; k < D; k += 4) {
            float4 xv = *(const float4*)(xr + k);  // wave-uniform broadcast load
            acc = fmaf(xv.x, sW[(k + 0) * 64 + lane], acc);
            acc = fmaf(xv.y, sW[(k + 1) * 64 + lane], acc);
            acc = fmaf(xv.z, sW[(k + 2) * 64 + lane], acc);
            acc = fmaf(xv.w, sW[(k + 3) * 64 + lane], acc);
        }
        out[(size_t)node * 64 + lane] = acc * dinv[node];
    }
}

// One wave per dst node; lane = feature. Pure gather+add over CSR (xl is
// pre-scaled by dinv[src]); x4 unroll for memory-level parallelism.
__global__ __launch_bounds__(256) void k_agg(const float* __restrict__ xl,
                                             const int* __restrict__ row_off,
                                             const int* __restrict__ csr_src,
                                             const float* __restrict__ dinv,
                                             const float* __restrict__ bias,
                                             float* __restrict__ out, int N) {
    int wave = threadIdx.x >> 6, lane = threadIdx.x & 63;
    int node = blockIdx.x * 4 + wave;
    if (node >= N) return;
    int beg = row_off[node], end = row_off[node + 1];
    float a0 = xl[(size_t)node * 64 + lane];  // self loop (pre-scaled)
    float a1 = 0.f, a2 = 0.f, a3 = 0.f;
    int e = beg;
    for (; e + 4 <= end; e += 4) {
        int s0 = csr_src[e + 0], s1 = csr_src[e + 1];
        int s2 = csr_src[e + 2], s3 = csr_src[e + 3];
        a0 += xl[(size_t)s0 * 64 + lane];
        a1 += xl[(size_t)s1 * 64 + lane];
        a2 += xl[(size_t)s2 * 64 + lane];
        a3 += xl[(size_t)s3 * 64 + lane];
    }
    for (; e < end; ++e) a0 += xl[(size_t)csr_src[e] * 64 + lane];
    float acc = (a0 + a1) + (a2 + a3);
    out[(size_t)node * 64 + lane] = fmaxf(acc * dinv[node] + bias[lane], 0.f);
}

// Layer-2 aggregation with the final FC + sigmoid fused (64-lane reduction).
__global__ __launch_bounds__(256) void k_agg_fc(const float* __restrict__ xl,
                                                const int* __restrict__ row_off,
                                                const int* __restrict__ csr_src,
                                                const float* __restrict__ dinv,
                                                const float* __restrict__ bias,
                                                const float* __restrict__ Wfc,
                                                const float* __restrict__ bfc,
                                                float* __restrict__ out, int N) {
    int wave = threadIdx.x >> 6, lane = threadIdx.x & 63;
    int node = blockIdx.x * 4 + wave;
    if (node >= N) return;
    int beg = row_off[node], end = row_off[node + 1];
    float a0 = xl[(size_t)node * 64 + lane];
    float a1 = 0.f, a2 = 0.f, a3 = 0.f;
    int e = beg;
    for (; e + 4 <= end; e += 4) {
        int s0 = csr_src[e + 0], s1 = csr_src[e + 1];
        int s2 = csr_src[e + 2], s3 = csr_src[e + 3];
        a0 += xl[(size_t)s0 * 64 + lane];
        a1 += xl[(size_t)s1 * 64 + lane];
        a2 += xl[(size_t)s2 * 64 + lane];
        a3 += xl[(size_t)s3 * 64 + lane];
    }
    for (; e < end; ++e) a0 += xl[(size_t)csr_src[e] * 64 + lane];
    float acc = (a0 + a1) + (a2 + a3);
    float h = fmaxf(acc * dinv[node] + bias[lane], 0.f);
    float v = h * Wfc[lane];
#pragma unroll
    for (int m = 32; m >= 1; m >>= 1) v += __shfl_xor(v, m, 64);
    if (lane == 0) out[node] = 1.f / (1.f + expf(-(v + bfc[0])));
}

extern "C" void kernel_launch(void* const* d_in, const int* in_sizes, int n_in,
                              void* d_out, int out_size, void* d_ws, size_t ws_size,
                              hipStream_t stream) {
    const float* x   = (const float*)d_in[0];
    const int*   ei  = (const int*)d_in[1];   // [2, E]: row then col
    const float* W1  = (const float*)d_in[2];
    const float* b1  = (const float*)d_in[3];
    const float* W2  = (const float*)d_in[4];
    const float* b2  = (const float*)d_in[5];
    const float* Wfc = (const float*)d_in[6];
    const float* bfc = (const float*)d_in[7];
    float* out = (float*)d_out;

    const int H = in_sizes[3];          // 64
    const int D = in_sizes[2] / H;      // 128
    const int N = in_sizes[0] / D;      // 100000
    const int E = in_sizes[1] / 2;      // 1600000
    const int* row = ei;
    const int* col = ei + E;

    // Workspace carve-up (256B aligned slices)
    char* p = (char*)d_ws;
    auto carve = [&](size_t bytes) {
        char* r = p;
        p += (bytes + 255) & ~(size_t)255;
        return (void*)r;
    };
    int*   counts    = (int*)carve((size_t)N * 4);
    int*   cursor    = (int*)carve((size_t)N * 4);
    int*   row_off   = (int*)carve((size_t)(N + 1) * 4);
    float* dinv      = (float*)carve((size_t)N * 4);
    int*   csr_src   = (int*)carve((size_t)E * 4);
    int*   blockSums = (int*)carve((size_t)1024 * 4);
    float* bufA      = (float*)carve((size_t)N * 64 * 4);
    float* bufB      = (float*)carve((size_t)N * 64 * 4);
    (void)ws_size;

    const int TB = 256;
    const int NB = (N + TB - 1) / TB;   // 391 scan tiles (must be <= 1024)

    // 1. degree + normalization + CSR (shared by both layers)
    k_zero_int<<<(N + TB - 1) / TB, TB, 0, stream>>>(counts, N);
    k_count<<<(E + TB - 1) / TB, TB, 0, stream>>>(col, E, counts);
    k_dinv<<<(N + TB - 1) / TB, TB, 0, stream>>>(counts, dinv, N);
    k_blocksum<<<NB, TB, 0, stream>>>(counts, N, blockSums);
    k_scan_blocks<<<1, 1024, 0, stream>>>(blockSums, NB);
    k_scan_write<<<NB, TB, 0, stream>>>(counts, N, E, blockSums, row_off, cursor);
    k_fill<<<(E + TB - 1) / TB, TB, 0, stream>>>(row, col, E, cursor, csr_src);

    int aggGrid = (N + 3) / 4;
    // 2. layer 1: xl = (x@W1)*dinv ; h1 = relu(dinv*Agg(xl)+b1)
    k_gemm<128><<<1024, TB, 0, stream>>>(x, W1, dinv, bufA, N);
    k_agg<<<aggGrid, TB, 0, stream>>>(bufA, row_off, csr_src, dinv, b1, bufB, N);
    // 3. layer 2: xl2 = (h1@W2)*dinv ; out = sigmoid(relu(dinv*Agg(xl2)+b2) @ Wfc + bfc)
    k_gemm<64><<<2048, TB, 0, stream>>>(bufB, W2, dinv, bufA, N);
    k_agg_fc<<<aggGrid, TB, 0, stream>>>(bufA, row_off, csr_src, dinv, b2, Wfc, bfc, out, N);
}

// Round 4
// 506.791 us; speedup vs baseline: 1.9322x; 1.1737x over previous
//
#include <hip/hip_runtime.h>
#include <math.h>

// ---------------------------------------------------------------------------
// GCN: h1 = relu(Agg(x@W1)+b1); h2 = relu(Agg(h1@W2)+b2); out = sigmoid(h2@Wfc+bfc)
// Agg(xl)[dst] = dinv[dst] * ( sum_{src->dst} xl_s[src] + xl_s[dst] )
//   where xl_s[n] = (x@W)[n] * dinv[n]   (source-side norm folded into GEMM)
// R2: 3-phase device-wide scan (was 232us single-block).
// R3: dinv folded into GEMM epilogue; agg edge loop unrolled x4.
// R4: register-tiled GEMM (64x64 tile/block, 4x4 per thread, LDS-staged X,W)
//     replaces broadcast-load single-acc GEMM (128us -> ~25us predicted).
// ---------------------------------------------------------------------------

__global__ void k_zero_int(int* __restrict__ p, int n) {
    int i = blockIdx.x * blockDim.x + threadIdx.x;
    if (i < n) p[i] = 0;
}

__global__ void k_count(const int* __restrict__ col, int E, int* __restrict__ counts) {
    int e = blockIdx.x * blockDim.x + threadIdx.x;
    if (e < E) atomicAdd(&counts[col[e]], 1);
}

__global__ void k_dinv(const int* __restrict__ counts, float* __restrict__ dinv, int N) {
    int i = blockIdx.x * blockDim.x + threadIdx.x;
    if (i < N) dinv[i] = rsqrtf((float)(counts[i] + 1));  // +1 self loop
}

// --- three-phase exclusive scan of counts[N] -> row_off[N+1], cursor[N] ---
__global__ __launch_bounds__(256) void k_blocksum(const int* __restrict__ counts, int N,
                                                  int* __restrict__ blockSums) {
    __shared__ int waveSum[4];
    int i = blockIdx.x * 256 + threadIdx.x;
    int v = (i < N) ? counts[i] : 0;
#pragma unroll
    for (int m = 32; m >= 1; m >>= 1) v += __shfl_xor(v, m, 64);
    int wave = threadIdx.x >> 6, lane = threadIdx.x & 63;
    if (lane == 0) waveSum[wave] = v;
    __syncthreads();
    if (threadIdx.x == 0)
        blockSums[blockIdx.x] = waveSum[0] + waveSum[1] + waveSum[2] + waveSum[3];
}

__global__ __launch_bounds__(1024) void k_scan_blocks(int* __restrict__ blockSums, int NB) {
    __shared__ int s[1024];
    int tid = threadIdx.x;
    int v = (tid < NB) ? blockSums[tid] : 0;
    s[tid] = v;
    __syncthreads();
    for (int off = 1; off < 1024; off <<= 1) {
        int t = (tid >= off) ? s[tid - off] : 0;
        __syncthreads();
        s[tid] += t;
        __syncthreads();
    }
    if (tid < NB) blockSums[tid] = s[tid] - v;  // exclusive
}

__global__ __launch_bounds__(256) void k_scan_write(const int* __restrict__ counts, int N, int E,
                                                    const int* __restrict__ blockOff,
                                                    int* __restrict__ row_off,
                                                    int* __restrict__ cursor) {
    __shared__ int s[256];
    int tid = threadIdx.x;
    int i = blockIdx.x * 256 + tid;
    int v = (i < N) ? counts[i] : 0;
    s[tid] = v;
    __syncthreads();
    for (int off = 1; off < 256; off <<= 1) {
        int t = (tid >= off) ? s[tid - off] : 0;
        __syncthreads();
        s[tid] += t;
        __syncthreads();
    }
    if (i < N) {
        int excl = blockOff[blockIdx.x] + s[tid] - v;
        row_off[i] = excl;
        cursor[i]  = excl;
        if (i == N - 1) row_off[N] = E;
    }
}

__global__ void k_fill(const int* __restrict__ row, const int* __restrict__ col, int E,
                       int* __restrict__ cursor, int* __restrict__ csr_src) {
    int e = blockIdx.x * blockDim.x + threadIdx.x;
    if (e < E) {
        int pos = atomicAdd(&cursor[col[e]], 1);
        csr_src[pos] = row[e];
    }
}

// Register-tiled GEMM: C[node][f] = dinv[node] * sum_k X[node][k]*W[k][f].
// Block: 256 threads -> 64 nodes x 64 feats; thread: 4 nodes x 4 feats.
// K processed in 64-wide slabs staged in LDS (sX stride 66 -> conflict-free).
template <int D>
__global__ __launch_bounds__(256) void k_gemm(const float* __restrict__ x,
                                              const float* __restrict__ W,
                                              const float* __restrict__ dinv,
                                              float* __restrict__ out, int N) {
    constexpr int KT = 64;
    constexpr int XS = KT + 2;          // sX row stride (66) -> banks 2r+kk, no conflict
    __shared__ float sX[64 * XS];       // 16.5 KB
    __shared__ float sW[D * 64];        // 32 KB (D=128) / 16 KB (D=64)
    const int tid = threadIdx.x;
    const int tile0 = blockIdx.x * 64;
    const int f0 = (tid & 15) * 4;      // feature quad
    const int n0 = (tid >> 4) * 4;      // node quad (within tile)

    // stage W once (contiguous float4, conflict-free)
    for (int i = tid; i < D * 16; i += 256)
        ((float4*)sW)[i] = ((const float4*)W)[i];

    float acc[4][4] = {};

    for (int p = 0; p < D; p += KT) {
        __syncthreads();                 // prev-phase readers done (also fences sW stage)
        // stage sX[r][c] = x[tile0+r][p+c], r,c in [0,64)
        for (int i = tid; i < 64 * 16; i += 256) {
            int r = i >> 4, c4 = (i & 15) * 4;
            int node = tile0 + r;
            float4 v = make_float4(0.f, 0.f, 0.f, 0.f);
            if (node < N) v = *(const float4*)(x + (size_t)node * D + p + c4);
            *(float4*)(&sX[r * XS + c4]) = v;
        }
        __syncthreads();
#pragma unroll
        for (int kk = 0; kk < KT; kk += 4) {
            float4 xv[4], wv[4];
#pragma unroll
            for (int j = 0; j < 4; ++j)
                xv[j] = *(const float4*)(&sX[(n0 + j) * XS + kk]);
#pragma unroll
            for (int i = 0; i < 4; ++i)
                wv[i] = *(const float4*)(&sW[(p + kk + i) * 64 + f0]);
#pragma unroll
            for (int i = 0; i < 4; ++i) {       // k within chunk
#pragma unroll
                for (int j = 0; j < 4; ++j) {   // node
                    float xs = (i == 0) ? xv[j].x : (i == 1) ? xv[j].y
                             : (i == 2) ? xv[j].z : xv[j].w;
                    acc[j][0] = fmaf(xs, wv[i].x, acc[j][0]);
                    acc[j][1] = fmaf(xs, wv[i].y, acc[j][1]);
                    acc[j][2] = fmaf(xs, wv[i].z, acc[j][2]);
                    acc[j][3] = fmaf(xs, wv[i].w, acc[j][3]);
                }
            }
        }
    }
    // epilogue: scale by dinv, coalesced float4 stores
#pragma unroll
    for (int j = 0; j < 4; ++j) {
        int node = tile0 + n0 + j;
        if (node < N) {
            float s = dinv[node];
            float4 v = make_float4(acc[j][0] * s, acc[j][1] * s,
                                   acc[j][2] * s, acc[j][3] * s);
            *(float4*)(out + (size_t)node * 64 + f0) = v;
        }
    }
}

// One wave per dst node; lane = feature. Pure gather+add over CSR (xl is
// pre-scaled by dinv[src]); x4 unroll for memory-level parallelism.
__global__ __launch_bounds__(256) void k_agg(const float* __restrict__ xl,
                                             const int* __restrict__ row_off,
                                             const int* __restrict__ csr_src,
                                             const float* __restrict__ dinv,
                                             const float* __restrict__ bias,
                                             float* __restrict__ out, int N) {
    int wave = threadIdx.x >> 6, lane = threadIdx.x & 63;
    int node = blockIdx.x * 4 + wave;
    if (node >= N) return;
    int beg = row_off[node], end = row_off[node + 1];
    float a0 = xl[(size_t)node * 64 + lane];  // self loop (pre-scaled)
    float a1 = 0.f, a2 = 0.f, a3 = 0.f;
    int e = beg;
    for (; e + 4 <= end; e += 4) {
        int s0 = csr_src[e + 0], s1 = csr_src[e + 1];
        int s2 = csr_src[e + 2], s3 = csr_src[e + 3];
        a0 += xl[(size_t)s0 * 64 + lane];
        a1 += xl[(size_t)s1 * 64 + lane];
        a2 += xl[(size_t)s2 * 64 + lane];
        a3 += xl[(size_t)s3 * 64 + lane];
    }
    for (; e < end; ++e) a0 += xl[(size_t)csr_src[e] * 64 + lane];
    float acc = (a0 + a1) + (a2 + a3);
    out[(size_t)node * 64 + lane] = fmaxf(acc * dinv[node] + bias[lane], 0.f);
}

// Layer-2 aggregation with the final FC + sigmoid fused (64-lane reduction).
__global__ __launch_bounds__(256) void k_agg_fc(const float* __restrict__ xl,
                                                const int* __restrict__ row_off,
                                                const int* __restrict__ csr_src,
                                                const float* __restrict__ dinv,
                                                const float* __restrict__ bias,
                                                const float* __restrict__ Wfc,
                                                const float* __restrict__ bfc,
                                                float* __restrict__ out, int N) {
    int wave = threadIdx.x >> 6, lane = threadIdx.x & 63;
    int node = blockIdx.x * 4 + wave;
    if (node >= N) return;
    int beg = row_off[node], end = row_off[node + 1];
    float a0 = xl[(size_t)node * 64 + lane];
    float a1 = 0.f, a2 = 0.f, a3 = 0.f;
    int e = beg;
    for (; e + 4 <= end; e += 4) {
        int s0 = csr_src[e + 0], s1 = csr_src[e + 1];
        int s2 = csr_src[e + 2], s3 = csr_src[e + 3];
        a0 += xl[(size_t)s0 * 64 + lane];
        a1 += xl[(size_t)s1 * 64 + lane];
        a2 += xl[(size_t)s2 * 64 + lane];
        a3 += xl[(size_t)s3 * 64 + lane];
    }
    for (; e < end; ++e) a0 += xl[(size_t)csr_src[e] * 64 + lane];
    float acc = (a0 + a1) + (a2 + a3);
    float h = fmaxf(acc * dinv[node] + bias[lane], 0.f);
    float v = h * Wfc[lane];
#pragma unroll
    for (int m = 32; m >= 1; m >>= 1) v += __shfl_xor(v, m, 64);
    if (lane == 0) out[node] = 1.f / (1.f + expf(-(v + bfc[0])));
}

extern "C" void kernel_launch(void* const* d_in, const int* in_sizes, int n_in,
                              void* d_out, int out_size, void* d_ws, size_t ws_size,
                              hipStream_t stream) {
    const float* x   = (const float*)d_in[0];
    const int*   ei  = (const int*)d_in[1];   // [2, E]: row then col
    const float* W1  = (const float*)d_in[2];
    const float* b1  = (const float*)d_in[3];
    const float* W2  = (const float*)d_in[4];
    const float* b2  = (const float*)d_in[5];
    const float* Wfc = (const float*)d_in[6];
    const float* bfc = (const float*)d_in[7];
    float* out = (float*)d_out;

    const int H = in_sizes[3];          // 64
    const int D = in_sizes[2] / H;      // 128
    const int N = in_sizes[0] / D;      // 100000
    const int E = in_sizes[1] / 2;      // 1600000
    const int* row = ei;
    const int* col = ei + E;

    // Workspace carve-up (256B aligned slices)
    char* p = (char*)d_ws;
    auto carve = [&](size_t bytes) {
        char* r = p;
        p += (bytes + 255) & ~(size_t)255;
        return (void*)r;
    };
    int*   counts    = (int*)carve((size_t)N * 4);
    int*   cursor    = (int*)carve((size_t)N * 4);
    int*   row_off   = (int*)carve((size_t)(N + 1) * 4);
    float* dinv      = (float*)carve((size_t)N * 4);
    int*   csr_src   = (int*)carve((size_t)E * 4);
    int*   blockSums = (int*)carve((size_t)1024 * 4);
    float* bufA      = (float*)carve((size_t)N * 64 * 4);
    float* bufB      = (float*)carve((size_t)N * 64 * 4);
    (void)ws_size;

    const int TB = 256;
    const int NB = (N + TB - 1) / TB;   // 391 scan tiles (must be <= 1024)

    // 1. degree + normalization + CSR (shared by both layers)
    k_zero_int<<<(N + TB - 1) / TB, TB, 0, stream>>>(counts, N);
    k_count<<<(E + TB - 1) / TB, TB, 0, stream>>>(col, E, counts);
    k_dinv<<<(N + TB - 1) / TB, TB, 0, stream>>>(counts, dinv, N);
    k_blocksum<<<NB, TB, 0, stream>>>(counts, N, blockSums);
    k_scan_blocks<<<1, 1024, 0, stream>>>(blockSums, NB);
    k_scan_write<<<NB, TB, 0, stream>>>(counts, N, E, blockSums, row_off, cursor);
    k_fill<<<(E + TB - 1) / TB, TB, 0, stream>>>(row, col, E, cursor, csr_src);

    int gemmGrid = (N + 63) / 64;       // 1563
    int aggGrid  = (N + 3) / 4;
    // 2. layer 1: xl = (x@W1)*dinv ; h1 = relu(dinv*Agg(xl)+b1)
    k_gemm<128><<<gemmGrid, TB, 0, stream>>>(x, W1, dinv, bufA, N);
    k_agg<<<aggGrid, TB, 0, stream>>>(bufA, row_off, csr_src, dinv, b1, bufB, N);
    // 3. layer 2: xl2 = (h1@W2)*dinv ; out = sigmoid(relu(dinv*Agg(xl2)+b2) @ Wfc + bfc)
    k_gemm<64><<<gemmGrid, TB, 0, stream>>>(bufB, W2, dinv, bufA, N);
    k_agg_fc<<<aggGrid, TB, 0, stream>>>(bufA, row_off, csr_src, dinv, b2, Wfc, bfc, out, N);
}

// Round 5
// 467.107 us; speedup vs baseline: 2.0964x; 1.0850x over previous
//
#include <hip/hip_runtime.h>
#include <math.h>

// ---------------------------------------------------------------------------
// GCN: h1 = relu(Agg(x@W1)+b1); h2 = relu(Agg(h1@W2)+b2); out = sigmoid(h2@Wfc+bfc)
// Agg(xl)[dst] = dinv[dst] * ( sum_{src->dst} xl_s[src] + xl_s[dst] )
//   where xl_s[n] = (x@W)[n] * dinv[n]   (source-side norm folded into GEMM)
// R2: 3-phase device-wide scan (was 232us single-block).
// R3: dinv folded into GEMM epilogue; agg edge loop unrolled x4.
// R4: register-tiled GEMM (64x64 tile/block, 4x4/thread, LDS X,W).
// R5: dst-class-sharded k_count/k_fill: 8 dst classes, class = blockIdx&7
//     (round-robin XCD heuristic) -> scatter writes/atomics localize to one
//     XCD's L2, killing the 16x write amplification (105MB -> ~12MB).
// ---------------------------------------------------------------------------

__global__ void k_zero_int(int* __restrict__ p, int n) {
    int i = blockIdx.x * blockDim.x + threadIdx.x;
    if (i < n) p[i] = 0;
}

// Class-sharded degree count: block handles dsts in [cls*Q, (cls+1)*Q).
__global__ __launch_bounds__(256) void k_count(const int* __restrict__ col, int E, int Q,
                                               int* __restrict__ counts) {
    const int cls = blockIdx.x & 7;
    const int nb  = gridDim.x >> 3;
    const int bi  = blockIdx.x >> 3;
    const unsigned lo = (unsigned)(cls * Q);
    for (int e = bi * 256 + threadIdx.x; e < E; e += nb * 256) {
        int d = col[e];
        if ((unsigned)(d - lo) < (unsigned)Q) atomicAdd(&counts[d], 1);
    }
}

__global__ void k_dinv(const int* __restrict__ counts, float* __restrict__ dinv, int N) {
    int i = blockIdx.x * blockDim.x + threadIdx.x;
    if (i < N) dinv[i] = rsqrtf((float)(counts[i] + 1));  // +1 self loop
}

// --- three-phase exclusive scan of counts[N] -> row_off[N+1], cursor[N] ---
__global__ __launch_bounds__(256) void k_blocksum(const int* __restrict__ counts, int N,
                                                  int* __restrict__ blockSums) {
    __shared__ int waveSum[4];
    int i = blockIdx.x * 256 + threadIdx.x;
    int v = (i < N) ? counts[i] : 0;
#pragma unroll
    for (int m = 32; m >= 1; m >>= 1) v += __shfl_xor(v, m, 64);
    int wave = threadIdx.x >> 6, lane = threadIdx.x & 63;
    if (lane == 0) waveSum[wave] = v;
    __syncthreads();
    if (threadIdx.x == 0)
        blockSums[blockIdx.x] = waveSum[0] + waveSum[1] + waveSum[2] + waveSum[3];
}

__global__ __launch_bounds__(1024) void k_scan_blocks(int* __restrict__ blockSums, int NB) {
    __shared__ int s[1024];
    int tid = threadIdx.x;
    int v = (tid < NB) ? blockSums[tid] : 0;
    s[tid] = v;
    __syncthreads();
    for (int off = 1; off < 1024; off <<= 1) {
        int t = (tid >= off) ? s[tid - off] : 0;
        __syncthreads();
        s[tid] += t;
        __syncthreads();
    }
    if (tid < NB) blockSums[tid] = s[tid] - v;  // exclusive
}

__global__ __launch_bounds__(256) void k_scan_write(const int* __restrict__ counts, int N, int E,
                                                    const int* __restrict__ blockOff,
                                                    int* __restrict__ row_off,
                                                    int* __restrict__ cursor) {
    __shared__ int s[256];
    int tid = threadIdx.x;
    int i = blockIdx.x * 256 + tid;
    int v = (i < N) ? counts[i] : 0;
    s[tid] = v;
    __syncthreads();
    for (int off = 1; off < 256; off <<= 1) {
        int t = (tid >= off) ? s[tid - off] : 0;
        __syncthreads();
        s[tid] += t;
        __syncthreads();
    }
    if (i < N) {
        int excl = blockOff[blockIdx.x] + s[tid] - v;
        row_off[i] = excl;
        cursor[i]  = excl;
        if (i == N - 1) row_off[N] = E;
    }
}

// Class-sharded CSR fill: all writes/atomics for a dst class come from blocks
// with the same blockIdx&7 (-> same XCD under round-robin dispatch), so csr
// lines stay in one L2 and are written back once.
__global__ __launch_bounds__(256) void k_fill(const int* __restrict__ row,
                                              const int* __restrict__ col, int E, int Q,
                                              int* __restrict__ cursor,
                                              int* __restrict__ csr_src) {
    const int cls = blockIdx.x & 7;
    const int nb  = gridDim.x >> 3;
    const int bi  = blockIdx.x >> 3;
    const unsigned lo = (unsigned)(cls * Q);
    for (int e = bi * 256 + threadIdx.x; e < E; e += nb * 256) {
        int d = col[e];
        if ((unsigned)(d - lo) < (unsigned)Q) {
            int pos = atomicAdd(&cursor[d], 1);
            csr_src[pos] = row[e];
        }
    }
}

// Register-tiled GEMM: C[node][f] = dinv[node] * sum_k X[node][k]*W[k][f].
// Block: 256 threads -> 64 nodes x 64 feats; thread: 4 nodes x 4 feats.
template <int D>
__global__ __launch_bounds__(256) void k_gemm(const float* __restrict__ x,
                                              const float* __restrict__ W,
                                              const float* __restrict__ dinv,
                                              float* __restrict__ out, int N) {
    constexpr int KT = 64;
    constexpr int XS = KT + 2;          // sX row stride 66 -> conflict-free
    __shared__ float sX[64 * XS];
    __shared__ float sW[D * 64];
    const int tid = threadIdx.x;
    const int tile0 = blockIdx.x * 64;
    const int f0 = (tid & 15) * 4;      // feature quad
    const int n0 = (tid >> 4) * 4;      // node quad (within tile)

    for (int i = tid; i < D * 16; i += 256)
        ((float4*)sW)[i] = ((const float4*)W)[i];

    float acc[4][4] = {};

    for (int p = 0; p < D; p += KT) {
        __syncthreads();
        for (int i = tid; i < 64 * 16; i += 256) {
            int r = i >> 4, c4 = (i & 15) * 4;
            int node = tile0 + r;
            float4 v = make_float4(0.f, 0.f, 0.f, 0.f);
            if (node < N) v = *(const float4*)(x + (size_t)node * D + p + c4);
            *(float4*)(&sX[r * XS + c4]) = v;
        }
        __syncthreads();
#pragma unroll
        for (int kk = 0; kk < KT; kk += 4) {
            float4 xv[4], wv[4];
#pragma unroll
            for (int j = 0; j < 4; ++j)
                xv[j] = *(const float4*)(&sX[(n0 + j) * XS + kk]);
#pragma unroll
            for (int i = 0; i < 4; ++i)
                wv[i] = *(const float4*)(&sW[(p + kk + i) * 64 + f0]);
#pragma unroll
            for (int i = 0; i < 4; ++i) {
#pragma unroll
                for (int j = 0; j < 4; ++j) {
                    float xs = (i == 0) ? xv[j].x : (i == 1) ? xv[j].y
                             : (i == 2) ? xv[j].z : xv[j].w;
                    acc[j][0] = fmaf(xs, wv[i].x, acc[j][0]);
                    acc[j][1] = fmaf(xs, wv[i].y, acc[j][1]);
                    acc[j][2] = fmaf(xs, wv[i].z, acc[j][2]);
                    acc[j][3] = fmaf(xs, wv[i].w, acc[j][3]);
                }
            }
        }
    }
#pragma unroll
    for (int j = 0; j < 4; ++j) {
        int node = tile0 + n0 + j;
        if (node < N) {
            float s = dinv[node];
            float4 v = make_float4(acc[j][0] * s, acc[j][1] * s,
                                   acc[j][2] * s, acc[j][3] * s);
            *(float4*)(out + (size_t)node * 64 + f0) = v;
        }
    }
}

// One wave per dst node; lane = feature. Pure gather+add over CSR (xl is
// pre-scaled by dinv[src]); x4 unroll for memory-level parallelism.
__global__ __launch_bounds__(256) void k_agg(const float* __restrict__ xl,
                                             const int* __restrict__ row_off,
                                             const int* __restrict__ csr_src,
                                             const float* __restrict__ dinv,
                                             const float* __restrict__ bias,
                                             float* __restrict__ out, int N) {
    int wave = threadIdx.x >> 6, lane = threadIdx.x & 63;
    int node = blockIdx.x * 4 + wave;
    if (node >= N) return;
    int beg = row_off[node], end = row_off[node + 1];
    float a0 = xl[(size_t)node * 64 + lane];  // self loop (pre-scaled)
    float a1 = 0.f, a2 = 0.f, a3 = 0.f;
    int e = beg;
    for (; e + 4 <= end; e += 4) {
        int s0 = csr_src[e + 0], s1 = csr_src[e + 1];
        int s2 = csr_src[e + 2], s3 = csr_src[e + 3];
        a0 += xl[(size_t)s0 * 64 + lane];
        a1 += xl[(size_t)s1 * 64 + lane];
        a2 += xl[(size_t)s2 * 64 + lane];
        a3 += xl[(size_t)s3 * 64 + lane];
    }
    for (; e < end; ++e) a0 += xl[(size_t)csr_src[e] * 64 + lane];
    float acc = (a0 + a1) + (a2 + a3);
    out[(size_t)node * 64 + lane] = fmaxf(acc * dinv[node] + bias[lane], 0.f);
}

// Layer-2 aggregation with the final FC + sigmoid fused (64-lane reduction).
__global__ __launch_bounds__(256) void k_agg_fc(const float* __restrict__ xl,
                                                const int* __restrict__ row_off,
                                                const int* __restrict__ csr_src,
                                                const float* __restrict__ dinv,
                                                const float* __restrict__ bias,
                                                const float* __restrict__ Wfc,
                                                const float* __restrict__ bfc,
                                                float* __restrict__ out, int N) {
    int wave = threadIdx.x >> 6, lane = threadIdx.x & 63;
    int node = blockIdx.x * 4 + wave;
    if (node >= N) return;
    int beg = row_off[node], end = row_off[node + 1];
    float a0 = xl[(size_t)node * 64 + lane];
    float a1 = 0.f, a2 = 0.f, a3 = 0.f;
    int e = beg;
    for (; e + 4 <= end; e += 4) {
        int s0 = csr_src[e + 0], s1 = csr_src[e + 1];
        int s2 = csr_src[e + 2], s3 = csr_src[e + 3];
        a0 += xl[(size_t)s0 * 64 + lane];
        a1 += xl[(size_t)s1 * 64 + lane];
        a2 += xl[(size_t)s2 * 64 + lane];
        a3 += xl[(size_t)s3 * 64 + lane];
    }
    for (; e < end; ++e) a0 += xl[(size_t)csr_src[e] * 64 + lane];
    float acc = (a0 + a1) + (a2 + a3);
    float h = fmaxf(acc * dinv[node] + bias[lane], 0.f);
    float v = h * Wfc[lane];
#pragma unroll
    for (int m = 32; m >= 1; m >>= 1) v += __shfl_xor(v, m, 64);
    if (lane == 0) out[node] = 1.f / (1.f + expf(-(v + bfc[0])));
}

extern "C" void kernel_launch(void* const* d_in, const int* in_sizes, int n_in,
                              void* d_out, int out_size, void* d_ws, size_t ws_size,
                              hipStream_t stream) {
    const float* x   = (const float*)d_in[0];
    const int*   ei  = (const int*)d_in[1];   // [2, E]: row then col
    const float* W1  = (const float*)d_in[2];
    const float* b1  = (const float*)d_in[3];
    const float* W2  = (const float*)d_in[4];
    const float* b2  = (const float*)d_in[5];
    const float* Wfc = (const float*)d_in[6];
    const float* bfc = (const float*)d_in[7];
    float* out = (float*)d_out;

    const int H = in_sizes[3];          // 64
    const int D = in_sizes[2] / H;      // 128
    const int N = in_sizes[0] / D;      // 100000
    const int E = in_sizes[1] / 2;      // 1600000
    const int* row = ei;
    const int* col = ei + E;
    const int Q = (N + 7) / 8;          // dsts per class

    // Workspace carve-up (256B aligned slices)
    char* p = (char*)d_ws;
    auto carve = [&](size_t bytes) {
        char* r = p;
        p += (bytes + 255) & ~(size_t)255;
        return (void*)r;
    };
    int*   counts    = (int*)carve((size_t)N * 4);
    int*   cursor    = (int*)carve((size_t)N * 4);
    int*   row_off   = (int*)carve((size_t)(N + 1) * 4);
    float* dinv      = (float*)carve((size_t)N * 4);
    int*   csr_src   = (int*)carve((size_t)E * 4);
    int*   blockSums = (int*)carve((size_t)1024 * 4);
    float* bufA      = (float*)carve((size_t)N * 64 * 4);
    float* bufB      = (float*)carve((size_t)N * 64 * 4);
    (void)ws_size;

    const int TB = 256;
    const int NB = (N + TB - 1) / TB;   // 391 scan tiles (must be <= 1024)
    const int SHARD_GRID = 8 * 128;     // 8 classes x 128 blocks (=4/CU)

    // 1. degree + normalization + CSR (shared by both layers)
    k_zero_int<<<(N + TB - 1) / TB, TB, 0, stream>>>(counts, N);
    k_count<<<SHARD_GRID, TB, 0, stream>>>(col, E, Q, counts);
    k_dinv<<<(N + TB - 1) / TB, TB, 0, stream>>>(counts, dinv, N);
    k_blocksum<<<NB, TB, 0, stream>>>(counts, N, blockSums);
    k_scan_blocks<<<1, 1024, 0, stream>>>(blockSums, NB);
    k_scan_write<<<NB, TB, 0, stream>>>(counts, N, E, blockSums, row_off, cursor);
    k_fill<<<SHARD_GRID, TB, 0, stream>>>(row, col, E, Q, cursor, csr_src);

    int gemmGrid = (N + 63) / 64;       // 1563
    int aggGrid  = (N + 3) / 4;
    // 2. layer 1: xl = (x@W1)*dinv ; h1 = relu(dinv*Agg(xl)+b1)
    k_gemm<128><<<gemmGrid, TB, 0, stream>>>(x, W1, dinv, bufA, N);
    k_agg<<<aggGrid, TB, 0, stream>>>(bufA, row_off, csr_src, dinv, b1, bufB, N);
    // 3. layer 2: xl2 = (h1@W2)*dinv ; out = sigmoid(relu(dinv*Agg(xl2)+b2) @ Wfc + bfc)
    k_gemm<64><<<gemmGrid, TB, 0, stream>>>(bufB, W2, dinv, bufA, N);
    k_agg_fc<<<aggGrid, TB, 0, stream>>>(bufA, row_off, csr_src, dinv, b2, Wfc, bfc, out, N);
}

// Round 6
// 463.956 us; speedup vs baseline: 2.1106x; 1.0068x over previous
//
#include <hip/hip_runtime.h>
#include <math.h>

// ---------------------------------------------------------------------------
// GCN: h1 = relu(Agg(x@W1)+b1); h2 = relu(Agg(h1@W2)+b2); out = sigmoid(h2@Wfc+bfc)
// Agg(xl)[dst] = dinv[dst] * ( sum_{src->dst} xl_s[src] + xl_s[dst] )
//   where xl_s[n] = (x@W)[n] * dinv[n]   (source-side norm folded into GEMM)
// R2: 3-phase device-wide scan. R3: dinv folded into GEMM; agg unroll x4.
// R4: register-tiled GEMM (64x64/block, 4x4/thread).
// R5: dst-class-sharded count/fill (blockIdx&7 XCD heuristic) -> write amp gone.
// R6: bf16 gather buffers (GEMM epilogue emits bf16; agg gathers 128B/edge
//     instead of 256B) + edge unroll 4->8. Accumulation stays fp32.
// ---------------------------------------------------------------------------

__device__ __forceinline__ float bf2f(unsigned short h) {
    return __uint_as_float((unsigned)h << 16);
}
__device__ __forceinline__ unsigned short f2bf(float f) {
    unsigned u = __float_as_uint(f);
    u += 0x7FFFu + ((u >> 16) & 1u);   // round-to-nearest-even
    return (unsigned short)(u >> 16);
}

__global__ void k_zero_int(int* __restrict__ p, int n) {
    int i = blockIdx.x * blockDim.x + threadIdx.x;
    if (i < n) p[i] = 0;
}

// Class-sharded degree count: block handles dsts in [cls*Q, (cls+1)*Q).
__global__ __launch_bounds__(256) void k_count(const int* __restrict__ col, int E, int Q,
                                               int* __restrict__ counts) {
    const int cls = blockIdx.x & 7;
    const int nb  = gridDim.x >> 3;
    const int bi  = blockIdx.x >> 3;
    const unsigned lo = (unsigned)(cls * Q);
    for (int e = bi * 256 + threadIdx.x; e < E; e += nb * 256) {
        int d = col[e];
        if ((unsigned)(d - lo) < (unsigned)Q) atomicAdd(&counts[d], 1);
    }
}

__global__ void k_dinv(const int* __restrict__ counts, float* __restrict__ dinv, int N) {
    int i = blockIdx.x * blockDim.x + threadIdx.x;
    if (i < N) dinv[i] = rsqrtf((float)(counts[i] + 1));  // +1 self loop
}

// --- three-phase exclusive scan of counts[N] -> row_off[N+1], cursor[N] ---
__global__ __launch_bounds__(256) void k_blocksum(const int* __restrict__ counts, int N,
                                                  int* __restrict__ blockSums) {
    __shared__ int waveSum[4];
    int i = blockIdx.x * 256 + threadIdx.x;
    int v = (i < N) ? counts[i] : 0;
#pragma unroll
    for (int m = 32; m >= 1; m >>= 1) v += __shfl_xor(v, m, 64);
    int wave = threadIdx.x >> 6, lane = threadIdx.x & 63;
    if (lane == 0) waveSum[wave] = v;
    __syncthreads();
    if (threadIdx.x == 0)
        blockSums[blockIdx.x] = waveSum[0] + waveSum[1] + waveSum[2] + waveSum[3];
}

__global__ __launch_bounds__(1024) void k_scan_blocks(int* __restrict__ blockSums, int NB) {
    __shared__ int s[1024];
    int tid = threadIdx.x;
    int v = (tid < NB) ? blockSums[tid] : 0;
    s[tid] = v;
    __syncthreads();
    for (int off = 1; off < 1024; off <<= 1) {
        int t = (tid >= off) ? s[tid - off] : 0;
        __syncthreads();
        s[tid] += t;
        __syncthreads();
    }
    if (tid < NB) blockSums[tid] = s[tid] - v;  // exclusive
}

__global__ __launch_bounds__(256) void k_scan_write(const int* __restrict__ counts, int N, int E,
                                                    const int* __restrict__ blockOff,
                                                    int* __restrict__ row_off,
                                                    int* __restrict__ cursor) {
    __shared__ int s[256];
    int tid = threadIdx.x;
    int i = blockIdx.x * 256 + tid;
    int v = (i < N) ? counts[i] : 0;
    s[tid] = v;
    __syncthreads();
    for (int off = 1; off < 256; off <<= 1) {
        int t = (tid >= off) ? s[tid - off] : 0;
        __syncthreads();
        s[tid] += t;
        __syncthreads();
    }
    if (i < N) {
        int excl = blockOff[blockIdx.x] + s[tid] - v;
        row_off[i] = excl;
        cursor[i]  = excl;
        if (i == N - 1) row_off[N] = E;
    }
}

// Class-sharded CSR fill (same blockIdx&7 class -> same XCD heuristic).
__global__ __launch_bounds__(256) void k_fill(const int* __restrict__ row,
                                              const int* __restrict__ col, int E, int Q,
                                              int* __restrict__ cursor,
                                              int* __restrict__ csr_src) {
    const int cls = blockIdx.x & 7;
    const int nb  = gridDim.x >> 3;
    const int bi  = blockIdx.x >> 3;
    const unsigned lo = (unsigned)(cls * Q);
    for (int e = bi * 256 + threadIdx.x; e < E; e += nb * 256) {
        int d = col[e];
        if ((unsigned)(d - lo) < (unsigned)Q) {
            int pos = atomicAdd(&cursor[d], 1);
            csr_src[pos] = row[e];
        }
    }
}

// Register-tiled GEMM, bf16 output: xl[node][f] = bf16(dinv[node]*sum_k X*W).
// Block: 256 threads -> 64 nodes x 64 feats; thread: 4 nodes x 4 feats.
template <int D>
__global__ __launch_bounds__(256) void k_gemm(const float* __restrict__ x,
                                              const float* __restrict__ W,
                                              const float* __restrict__ dinv,
                                              unsigned short* __restrict__ out, int N) {
    constexpr int KT = 64;
    constexpr int XS = KT + 2;          // sX row stride 66 -> conflict-free
    __shared__ float sX[64 * XS];
    __shared__ float sW[D * 64];
    const int tid = threadIdx.x;
    const int tile0 = blockIdx.x * 64;
    const int f0 = (tid & 15) * 4;      // feature quad
    const int n0 = (tid >> 4) * 4;      // node quad (within tile)

    for (int i = tid; i < D * 16; i += 256)
        ((float4*)sW)[i] = ((const float4*)W)[i];

    float acc[4][4] = {};

    for (int p = 0; p < D; p += KT) {
        __syncthreads();
        for (int i = tid; i < 64 * 16; i += 256) {
            int r = i >> 4, c4 = (i & 15) * 4;
            int node = tile0 + r;
            float4 v = make_float4(0.f, 0.f, 0.f, 0.f);
            if (node < N) v = *(const float4*)(x + (size_t)node * D + p + c4);
            *(float4*)(&sX[r * XS + c4]) = v;
        }
        __syncthreads();
#pragma unroll
        for (int kk = 0; kk < KT; kk += 4) {
            float4 xv[4], wv[4];
#pragma unroll
            for (int j = 0; j < 4; ++j)
                xv[j] = *(const float4*)(&sX[(n0 + j) * XS + kk]);
#pragma unroll
            for (int i = 0; i < 4; ++i)
                wv[i] = *(const float4*)(&sW[(p + kk + i) * 64 + f0]);
#pragma unroll
            for (int i = 0; i < 4; ++i) {
#pragma unroll
                for (int j = 0; j < 4; ++j) {
                    float xs = (i == 0) ? xv[j].x : (i == 1) ? xv[j].y
                             : (i == 2) ? xv[j].z : xv[j].w;
                    acc[j][0] = fmaf(xs, wv[i].x, acc[j][0]);
                    acc[j][1] = fmaf(xs, wv[i].y, acc[j][1]);
                    acc[j][2] = fmaf(xs, wv[i].z, acc[j][2]);
                    acc[j][3] = fmaf(xs, wv[i].w, acc[j][3]);
                }
            }
        }
    }
#pragma unroll
    for (int j = 0; j < 4; ++j) {
        int node = tile0 + n0 + j;
        if (node < N) {
            float s = dinv[node];
            ushort4 v;
            v.x = f2bf(acc[j][0] * s);
            v.y = f2bf(acc[j][1] * s);
            v.z = f2bf(acc[j][2] * s);
            v.w = f2bf(acc[j][3] * s);
            *(ushort4*)(out + (size_t)node * 64 + f0) = v;  // 8B store
        }
    }
}

// Layer-1 agg: bf16 gather (128B/edge), fp32 accumulate, fp32 h1 out.
// One wave per dst node; lane = feature; 8-deep unroll for MLP.
__global__ __launch_bounds__(256) void k_agg(const unsigned short* __restrict__ xl,
                                             const int* __restrict__ row_off,
                                             const int* __restrict__ csr_src,
                                             const float* __restrict__ dinv,
                                             const float* __restrict__ bias,
                                             float* __restrict__ out, int N) {
    int wave = threadIdx.x >> 6, lane = threadIdx.x & 63;
    int node = blockIdx.x * 4 + wave;
    if (node >= N) return;
    int beg = row_off[node], end = row_off[node + 1];
    float a[8];
    a[0] = bf2f(xl[(size_t)node * 64 + lane]);  // self loop (pre-scaled)
#pragma unroll
    for (int j = 1; j < 8; ++j) a[j] = 0.f;
    int e = beg;
    for (; e + 8 <= end; e += 8) {
        int s[8];
#pragma unroll
        for (int j = 0; j < 8; ++j) s[j] = csr_src[e + j];
#pragma unroll
        for (int j = 0; j < 8; ++j) a[j] += bf2f(xl[(size_t)s[j] * 64 + lane]);
    }
    for (; e < end; ++e) a[0] += bf2f(xl[(size_t)csr_src[e] * 64 + lane]);
    float acc = ((a[0] + a[1]) + (a[2] + a[3])) + ((a[4] + a[5]) + (a[6] + a[7]));
    out[(size_t)node * 64 + lane] = fmaxf(acc * dinv[node] + bias[lane], 0.f);
}

// Layer-2 agg + final FC + sigmoid fused (64-lane shuffle reduction).
__global__ __launch_bounds__(256) void k_agg_fc(const unsigned short* __restrict__ xl,
                                                const int* __restrict__ row_off,
                                                const int* __restrict__ csr_src,
                                                const float* __restrict__ dinv,
                                                const float* __restrict__ bias,
                                                const float* __restrict__ Wfc,
                                                const float* __restrict__ bfc,
                                                float* __restrict__ out, int N) {
    int wave = threadIdx.x >> 6, lane = threadIdx.x & 63;
    int node = blockIdx.x * 4 + wave;
    if (node >= N) return;
    int beg = row_off[node], end = row_off[node + 1];
    float a[8];
    a[0] = bf2f(xl[(size_t)node * 64 + lane]);
#pragma unroll
    for (int j = 1; j < 8; ++j) a[j] = 0.f;
    int e = beg;
    for (; e + 8 <= end; e += 8) {
        int s[8];
#pragma unroll
        for (int j = 0; j < 8; ++j) s[j] = csr_src[e + j];
#pragma unroll
        for (int j = 0; j < 8; ++j) a[j] += bf2f(xl[(size_t)s[j] * 64 + lane]);
    }
    for (; e < end; ++e) a[0] += bf2f(xl[(size_t)csr_src[e] * 64 + lane]);
    float acc = ((a[0] + a[1]) + (a[2] + a[3])) + ((a[4] + a[5]) + (a[6] + a[7]));
    float h = fmaxf(acc * dinv[node] + bias[lane], 0.f);
    float v = h * Wfc[lane];
#pragma unroll
    for (int m = 32; m >= 1; m >>= 1) v += __shfl_xor(v, m, 64);
    if (lane == 0) out[node] = 1.f / (1.f + expf(-(v + bfc[0])));
}

extern "C" void kernel_launch(void* const* d_in, const int* in_sizes, int n_in,
                              void* d_out, int out_size, void* d_ws, size_t ws_size,
                              hipStream_t stream) {
    const float* x   = (const float*)d_in[0];
    const int*   ei  = (const int*)d_in[1];   // [2, E]: row then col
    const float* W1  = (const float*)d_in[2];
    const float* b1  = (const float*)d_in[3];
    const float* W2  = (const float*)d_in[4];
    const float* b2  = (const float*)d_in[5];
    const float* Wfc = (const float*)d_in[6];
    const float* bfc = (const float*)d_in[7];
    float* out = (float*)d_out;

    const int H = in_sizes[3];          // 64
    const int D = in_sizes[2] / H;      // 128
    const int N = in_sizes[0] / D;      // 100000
    const int E = in_sizes[1] / 2;      // 1600000
    const int* row = ei;
    const int* col = ei + E;
    const int Q = (N + 7) / 8;          // dsts per class

    // Workspace carve-up (256B aligned slices)
    char* p = (char*)d_ws;
    auto carve = [&](size_t bytes) {
        char* r = p;
        p += (bytes + 255) & ~(size_t)255;
        return (void*)r;
    };
    int*            counts    = (int*)carve((size_t)N * 4);
    int*            cursor    = (int*)carve((size_t)N * 4);
    int*            row_off   = (int*)carve((size_t)(N + 1) * 4);
    float*          dinv      = (float*)carve((size_t)N * 4);
    int*            csr_src   = (int*)carve((size_t)E * 4);
    int*            blockSums = (int*)carve((size_t)1024 * 4);
    unsigned short* bufXL     = (unsigned short*)carve((size_t)N * 64 * 2);  // bf16 gather buf
    float*          bufH      = (float*)carve((size_t)N * 64 * 4);           // fp32 h1
    (void)ws_size;

    const int TB = 256;
    const int NB = (N + TB - 1) / TB;   // 391 scan tiles (must be <= 1024)
    const int SHARD_GRID = 8 * 128;     // 8 classes x 128 blocks

    // 1. degree + normalization + CSR (shared by both layers)
    k_zero_int<<<(N + TB - 1) / TB, TB, 0, stream>>>(counts, N);
    k_count<<<SHARD_GRID, TB, 0, stream>>>(col, E, Q, counts);
    k_dinv<<<(N + TB - 1) / TB, TB, 0, stream>>>(counts, dinv, N);
    k_blocksum<<<NB, TB, 0, stream>>>(counts, N, blockSums);
    k_scan_blocks<<<1, 1024, 0, stream>>>(blockSums, NB);
    k_scan_write<<<NB, TB, 0, stream>>>(counts, N, E, blockSums, row_off, cursor);
    k_fill<<<SHARD_GRID, TB, 0, stream>>>(row, col, E, Q, cursor, csr_src);

    int gemmGrid = (N + 63) / 64;       // 1563
    int aggGrid  = (N + 3) / 4;
    // 2. layer 1: xl = bf16((x@W1)*dinv) ; h1 = relu(dinv*Agg(xl)+b1)  [fp32]
    k_gemm<128><<<gemmGrid, TB, 0, stream>>>(x, W1, dinv, bufXL, N);
    k_agg<<<aggGrid, TB, 0, stream>>>(bufXL, row_off, csr_src, dinv, b1, bufH, N);
    // 3. layer 2: xl2 = bf16((h1@W2)*dinv) ; out = sigmoid(relu(dinv*Agg+b2)@Wfc+bfc)
    k_gemm<64><<<gemmGrid, TB, 0, stream>>>(bufH, W2, dinv, bufXL, N);
    k_agg_fc<<<aggGrid, TB, 0, stream>>>(bufXL, row_off, csr_src, dinv, b2, Wfc, bfc, out, N);
}